// Round 5
// baseline (112.625 us; speedup 1.0000x reference)
//
#include <hip/hip_runtime.h>

// LSA, 2-kernel pipeline (R4-verified pieces, K_ST+K_V fused via LDS):
//   K_T : fmap[b][c][hw] f32 -> fT[b][n][c] bf16 (verbatim R4, verified)
//   K_F : per 4x16-px tile: s[n][k] = sum_l attn[n,l]*fT[nbr(n,l)][k] (R4 stencil,
//         verified) -> LDS s_tile -> out = fmap + gamma * Wv @ s (R4 MFMA GEMM,
//         verified; B-fragments now from LDS instead of global sT).
// B=4, C=128, H=64, W=128, L=25.

namespace {
constexpr int Bn = 4, Cn = 128, Hn = 64, Wn = 128, Ln = 25;
constexpr int HWn = Hn * Wn;  // 8192

typedef __attribute__((ext_vector_type(8))) short short8;
typedef __attribute__((ext_vector_type(4))) float f32x4;

__device__ inline unsigned short f2bf(float f) {
    unsigned u = __float_as_uint(f);
    return (unsigned short)((u + 0x7fffu + ((u >> 16) & 1u)) >> 16);  // RNE
}

// ---------------- K_T: transpose fmap -> fT (bf16), convert Wv (verbatim R4) ----
__global__ __launch_bounds__(256) void k_transpose(
    const float* __restrict__ fmap, const float* __restrict__ Wv,
    unsigned short* __restrict__ fT, unsigned short* __restrict__ wvb)
{
    __shared__ float tile[Cn][33];
    const int tid = threadIdx.x;
    const int b = blockIdx.y;
    const int n0 = blockIdx.x * 32;

    if (blockIdx.x == 0 && b == 0) {
        for (int i = tid; i < Cn * Cn; i += 256) wvb[i] = f2bf(Wv[i]);
    }
    for (int i = tid; i < Cn * 8; i += 256) {
        int c = i >> 3, q = i & 7;
        float4 v = *(const float4*)&fmap[((size_t)(b * Cn + c)) * HWn + n0 + q * 4];
        tile[c][q * 4 + 0] = v.x; tile[c][q * 4 + 1] = v.y;
        tile[c][q * 4 + 2] = v.z; tile[c][q * 4 + 3] = v.w;
    }
    __syncthreads();
    for (int i = tid; i < 32 * 64; i += 256) {
        int n = i >> 6, cp = i & 63;
        unsigned lo = f2bf(tile[2 * cp][n]), hi = f2bf(tile[2 * cp + 1][n]);
        *(unsigned*)&fT[((size_t)(b * HWn + n0 + n)) * Cn + 2 * cp] = lo | (hi << 16);
    }
}

// ---------------- K_F: stencil (R4 K_ST) + GEMM (R4 K_V) fused --------------
constexpr int TY = 4, TX = 16;   // output tile: 64 px
constexpr int HY = 8, HX = 24;   // halo
constexpr int RS = 136;          // halo row stride (halves)
constexpr int STS = 136;         // s_tile row stride (halves); row = 128 k + pad

__global__ __launch_bounds__(256) void k_fused(
    const unsigned short* __restrict__ fT, const float* __restrict__ attn,
    const unsigned short* __restrict__ wvb, const float* __restrict__ fmap,
    const float* __restrict__ gamma, float* __restrict__ out)
{
    __shared__ unsigned short hs[HY * HX * RS];   // 52.2 KB
    __shared__ float at_s[TY * TX * Ln];          // 6.4 KB
    __shared__ unsigned short s_tile[64 * STS];   // 17.4 KB

    const int tid = threadIdx.x;
    const int b = blockIdx.z;
    const int x0 = blockIdx.x * TX;
    const int y0 = blockIdx.y * TY;
    const float g = gamma[0];

    // ---- stage halo + attn (verbatim R4 K_ST) ----
    for (int i = tid; i < HY * HX * 16; i += 256) {
        int dy = i / (HX * 16), r = i - dy * (HX * 16);
        int hx = r >> 4, t = r & 15;
        int ry = min(max(y0 + dy - 2, 0), Hn - 1);
        int gx = min(max(x0 + hx - 4, 0), Wn - 1);
        *(uint4*)&hs[(dy * HX + hx) * RS + t * 8] =
            *(const uint4*)&fT[((size_t)(b * HWn + ry * Wn + gx)) * Cn + t * 8];
    }
    for (int i = tid; i < TY * TX * Ln; i += 256) {
        int p = i / Ln, l = i - p * Ln;
        int n = (y0 + (p >> 4)) * Wn + x0 + (p & 15);
        at_s[i] = attn[((size_t)b * HWn + n) * Ln + l];
    }
    __syncthreads();

    // ---- stencil (verbatim R4 K_ST), result -> LDS s_tile ----
    const int xi = tid & 15, kq = (tid >> 4) & 3, yi = tid >> 6;
    const int p = yi * 16 + xi;
    {
        float acc[32];
#pragma unroll
        for (int j = 0; j < 32; ++j) acc[j] = 0.f;
#pragma unroll
        for (int l = 0; l < Ln; ++l) {
            const int dy = l / 5, dx = l % 5;
            const float a = at_s[p * Ln + l];
            const unsigned short* row = &hs[((yi + dy) * HX + (2 + xi + dx)) * RS + kq * 32];
#pragma unroll
            for (int q = 0; q < 4; ++q) {
                uint4 u = *(const uint4*)&row[q * 8];
                const unsigned w[4] = {u.x, u.y, u.z, u.w};
#pragma unroll
                for (int e = 0; e < 4; ++e) {
                    acc[q * 8 + 2 * e + 0] += a * __uint_as_float(w[e] << 16);
                    acc[q * 8 + 2 * e + 1] += a * __uint_as_float(w[e] & 0xffff0000u);
                }
            }
        }
        unsigned short* dst = &s_tile[p * STS + kq * 32];
#pragma unroll
        for (int q = 0; q < 4; ++q) {
            unsigned pk[4];
#pragma unroll
            for (int e = 0; e < 4; ++e)
                pk[e] = (unsigned)f2bf(acc[q * 8 + 2 * e]) |
                        ((unsigned)f2bf(acc[q * 8 + 2 * e + 1]) << 16);
            uint4 v; v.x = pk[0]; v.y = pk[1]; v.z = pk[2]; v.w = pk[3];
            *(uint4*)&dst[q * 8] = v;
        }
    }
    __syncthreads();

    // ---- GEMM + epilogue (R4 K_V; B-frags from LDS s_tile) ----
    const int wave = tid >> 6, lane = tid & 63;
    const int m16 = lane & 15, q = lane >> 4;
    // wave handles pixel row yi=wave: n = (y0+wave)*Wn + x0 + m16, all 128 ch

    short8 bfrag[4];
    const unsigned short* srow = &s_tile[(wave * 16 + m16) * STS + q * 8];
#pragma unroll
    for (int kk = 0; kk < 4; ++kk) bfrag[kk] = *(const short8*)(srow + kk * 32);

#pragma unroll
    for (int mg = 0; mg < 8; ++mg) {
        const unsigned short* arow = &wvb[(size_t)(mg * 16 + m16) * Cn + q * 8];
        f32x4 acc = {0.f, 0.f, 0.f, 0.f};
#pragma unroll
        for (int kk = 0; kk < 4; ++kk) {
            short8 af = *(const short8*)(arow + kk * 32);
            acc = __builtin_amdgcn_mfma_f32_16x16x32_bf16(af, bfrag[kk], acc, 0, 0, 0);
        }
        // D: col = lane&15 = px-in-row, row = q*4+r = channel-within-16
#pragma unroll
        for (int r = 0; r < 4; ++r) {
            const int c = mg * 16 + q * 4 + r;
            const size_t idx = ((size_t)(b * Cn + c)) * HWn + (y0 + wave) * Wn + x0 + m16;
            out[idx] = fmap[idx] + g * acc[r];
        }
    }
}
}  // namespace

extern "C" void kernel_launch(void* const* d_in, const int* in_sizes, int n_in,
                              void* d_out, int out_size, void* d_ws, size_t ws_size,
                              hipStream_t stream) {
    const float* attn  = (const float*)d_in[0];
    const float* fmap  = (const float*)d_in[1];
    const float* Wv    = (const float*)d_in[2];
    const float* gamma = (const float*)d_in[3];
    float* out = (float*)d_out;

    // ws layout: fT 8.39 MB | wvb 32 KB
    unsigned short* fT  = (unsigned short*)d_ws;
    unsigned short* wvb = fT + (size_t)Bn * HWn * Cn;

    dim3 gT(HWn / 32, Bn);            // 256 x 4
    k_transpose<<<gT, 256, 0, stream>>>(fmap, Wv, fT, wvb);

    dim3 gF(Wn / TX, Hn / TY, Bn);    // 8 x 16 x 4 = 512
    k_fused<<<gF, 256, 0, stream>>>(fT, attn, wvb, fmap, gamma, out);
}